// Round 2
// baseline (474.763 us; speedup 1.0000x reference)
//
#include <hip/hip_runtime.h>

#define HDIM 64
#define TDIM 512

// One wave (64 lanes) per batch element. All f32.
// Lane i owns h[i] and row i of W_hh (64 f32 in VGPRs, loaded once).
// Per timestep: h_new[i] = tanh(x_t*W_ih[i] + bias[i] + sum_j W_hh[i][j]*h[j])
// h[j] broadcast to all lanes via v_readlane (uniform index -> SGPR operand).
__global__ __launch_bounds__(256, 4)
void rnn_wave_per_batch_f32(const float* __restrict__ x,
                            const float* __restrict__ W_ih,
                            const float* __restrict__ W_hh,
                            const float* __restrict__ b_ih,
                            const float* __restrict__ b_hh,
                            const float* __restrict__ fc_w,
                            const float* __restrict__ fc_b,
                            float* __restrict__ out,
                            int B)
{
    const int lane  = threadIdx.x & 63;
    const int batch = blockIdx.x * (blockDim.x >> 6) + (threadIdx.x >> 6);
    if (batch >= B) return;   // wave-uniform

    // --- load W_hh row `lane` (64 f32 = 256 B contiguous) into regs ---
    float w[HDIM];
    const float4* wp = (const float4*)(W_hh + lane * HDIM);  // 256B-aligned per lane
#pragma unroll
    for (int c = 0; c < HDIM / 4; ++c) {
        float4 q = wp[c];
        w[c*4+0] = q.x; w[c*4+1] = q.y; w[c*4+2] = q.z; w[c*4+3] = q.w;
    }

    const float w_ih_l = W_ih[lane];                 // I == 1
    const float bias_l = b_ih[lane] + b_hh[lane];

    const float* xb = x + (size_t)batch * TDIM;      // x[batch][t], I==1
    int xraw = __builtin_bit_cast(int, xb[lane]);    // lane holds x[t=lane] of chunk 0
    float h = 0.0f;

    const float TWO_LOG2E = 2.885390081777927f;      // 2*log2(e)

    for (int c = 0; c < TDIM / 64; ++c) {
        // prefetch next 64 timesteps of x (coalesced 256B per wave)
        int xnext = 0;
        if (c + 1 < TDIM / 64)
            xnext = __builtin_bit_cast(int, xb[(c + 1) * 64 + lane]);

#pragma unroll 1   // keep body ~160 instr; fits I$
        for (int j = 0; j < 64; ++j) {
            // broadcast x_t (uniform j -> readlane into SGPR)
            float xt = __builtin_bit_cast(float,
                        __builtin_amdgcn_readlane(xraw, j));

            int hb = __builtin_bit_cast(int, h);
            float a0 = fmaf(xt, w_ih_l, bias_l);
            float a1 = 0.f, a2 = 0.f, a3 = 0.f;
#pragma unroll
            for (int k = 0; k < HDIM; k += 4) {
                float h0 = __builtin_bit_cast(float, __builtin_amdgcn_readlane(hb, k + 0));
                float h1 = __builtin_bit_cast(float, __builtin_amdgcn_readlane(hb, k + 1));
                float h2 = __builtin_bit_cast(float, __builtin_amdgcn_readlane(hb, k + 2));
                float h3 = __builtin_bit_cast(float, __builtin_amdgcn_readlane(hb, k + 3));
                a0 = fmaf(w[k + 0], h0, a0);
                a1 = fmaf(w[k + 1], h1, a1);
                a2 = fmaf(w[k + 2], h2, a2);
                a3 = fmaf(w[k + 3], h3, a3);
            }
            float z = (a0 + a1) + (a2 + a3);
            // tanh(z) = 1 - 2/(1 + e^{2z}); saturates correctly for large |z|
            float t = __builtin_amdgcn_exp2f(z * TWO_LOG2E);
            float r = __builtin_amdgcn_rcpf(t + 1.0f);
            h = fmaf(-2.0f, r, 1.0f);
        }
        xraw = xnext;
    }

    // out[batch] = sum_i h[i]*fc_w[i] + fc_b   (wave-wide butterfly reduce)
    float v = h * fc_w[lane];
#pragma unroll
    for (int off = 32; off > 0; off >>= 1)
        v += __shfl_xor(v, off, 64);

    if (lane == 0)
        out[batch] = v + fc_b[0];
}

extern "C" void kernel_launch(void* const* d_in, const int* in_sizes, int n_in,
                              void* d_out, int out_size, void* d_ws, size_t ws_size,
                              hipStream_t stream)
{
    const float* x    = (const float*)d_in[0];
    const float* W_ih = (const float*)d_in[1];
    const float* W_hh = (const float*)d_in[2];
    const float* b_ih = (const float*)d_in[3];
    const float* b_hh = (const float*)d_in[4];
    const float* fc_w = (const float*)d_in[5];
    const float* fc_b = (const float*)d_in[6];
    float* out = (float*)d_out;

    const int B = in_sizes[0] / TDIM;          // x is (B, T, 1)
    const int wavesPerBlock = 4;
    const int blocks = (B + wavesPerBlock - 1) / wavesPerBlock;

    rnn_wave_per_batch_f32<<<blocks, wavesPerBlock * 64, 0, stream>>>(
        x, W_ih, W_hh, b_ih, b_hh, fc_w, fc_b, out, B);
}

// Round 3
// 454.572 us; speedup vs baseline: 1.0444x; 1.0444x over previous
//
#include <hip/hip_runtime.h>

#define HDIM 64
#define TDIM 512

// One wave (64 lanes) per batch element. All f32.
// Lane i owns h[i] and row i of W_hh, held in 16 explicit float4 scalars
// (NOT an array -> cannot be demoted to scratch; round-2 counter showed
// VGPR_Count=48, i.e. the w[64] array was spilled, costing 2x).
// Per timestep: h_new[i] = tanh(x_t*W_ih[i] + bias[i] + sum_j W_hh[i][j]*h[j])
// h[j] broadcast to all lanes via v_readlane (uniform index -> SGPR operand).

__device__ __forceinline__ float rl(int v, int idx) {
    return __builtin_bit_cast(float, __builtin_amdgcn_readlane(v, idx));
}

__global__ __launch_bounds__(256, 2)   // relax VGPR cap to 256; we need ~90
void rnn_wave_per_batch_f32(const float* __restrict__ x,
                            const float* __restrict__ W_ih,
                            const float* __restrict__ W_hh,
                            const float* __restrict__ b_ih,
                            const float* __restrict__ b_hh,
                            const float* __restrict__ fc_w,
                            const float* __restrict__ fc_b,
                            float* __restrict__ out,
                            int B)
{
    const int lane  = threadIdx.x & 63;
    const int batch = blockIdx.x * (blockDim.x >> 6) + (threadIdx.x >> 6);
    if (batch >= B) return;   // wave-uniform

    // --- W_hh row `lane` (64 f32 = 256 B contiguous) in 16 float4 regs ---
    const float4* wp = (const float4*)(W_hh + lane * HDIM);
    const float4 w0  = wp[0],  w1  = wp[1],  w2  = wp[2],  w3  = wp[3];
    const float4 w4  = wp[4],  w5  = wp[5],  w6  = wp[6],  w7  = wp[7];
    const float4 w8  = wp[8],  w9  = wp[9],  w10 = wp[10], w11 = wp[11];
    const float4 w12 = wp[12], w13 = wp[13], w14 = wp[14], w15 = wp[15];

    const float w_ih_l = W_ih[lane];                 // I == 1
    const float bias_l = b_ih[lane] + b_hh[lane];

    const float* xb = x + (size_t)batch * TDIM;      // x[batch][t], I==1
    int xraw = __builtin_bit_cast(int, xb[lane]);    // lane holds x[t=lane] of chunk 0
    float h = 0.0f;

    const float TWO_LOG2E = 2.885390081777927f;      // 2*log2(e)

#define QUAD(W, base)                          \
    a0 = fmaf(W.x, rl(hb, (base) + 0), a0);    \
    a1 = fmaf(W.y, rl(hb, (base) + 1), a1);    \
    a2 = fmaf(W.z, rl(hb, (base) + 2), a2);    \
    a3 = fmaf(W.w, rl(hb, (base) + 3), a3);

    for (int c = 0; c < TDIM / 64; ++c) {
        // prefetch next 64 timesteps of x (coalesced 256B per wave)
        int xnext = 0;
        if (c + 1 < TDIM / 64)
            xnext = __builtin_bit_cast(int, xb[(c + 1) * 64 + lane]);

#pragma unroll 1   // keep body ~150 instr; fits I$
        for (int j = 0; j < 64; ++j) {
            // broadcast x_t (uniform j -> readlane into SGPR)
            float xt = rl(xraw, j);

            const int hb = __builtin_bit_cast(int, h);
            float a0 = fmaf(xt, w_ih_l, bias_l);
            float a1 = 0.f, a2 = 0.f, a3 = 0.f;
            QUAD(w0,   0)  QUAD(w1,   4)  QUAD(w2,   8)  QUAD(w3,  12)
            QUAD(w4,  16)  QUAD(w5,  20)  QUAD(w6,  24)  QUAD(w7,  28)
            QUAD(w8,  32)  QUAD(w9,  36)  QUAD(w10, 40)  QUAD(w11, 44)
            QUAD(w12, 48)  QUAD(w13, 52)  QUAD(w14, 56)  QUAD(w15, 60)
            float z = (a0 + a1) + (a2 + a3);
            // tanh(z) = 1 - 2/(1 + e^{2z}); saturates correctly for large |z|
            float t = __builtin_amdgcn_exp2f(z * TWO_LOG2E);
            float r = __builtin_amdgcn_rcpf(t + 1.0f);
            h = fmaf(-2.0f, r, 1.0f);
        }
        xraw = xnext;
    }
#undef QUAD

    // out[batch] = sum_i h[i]*fc_w[i] + fc_b   (wave-wide butterfly reduce)
    float v = h * fc_w[lane];
#pragma unroll
    for (int off = 32; off > 0; off >>= 1)
        v += __shfl_xor(v, off, 64);

    if (lane == 0)
        out[batch] = v + fc_b[0];
}

extern "C" void kernel_launch(void* const* d_in, const int* in_sizes, int n_in,
                              void* d_out, int out_size, void* d_ws, size_t ws_size,
                              hipStream_t stream)
{
    const float* x    = (const float*)d_in[0];
    const float* W_ih = (const float*)d_in[1];
    const float* W_hh = (const float*)d_in[2];
    const float* b_ih = (const float*)d_in[3];
    const float* b_hh = (const float*)d_in[4];
    const float* fc_w = (const float*)d_in[5];
    const float* fc_b = (const float*)d_in[6];
    float* out = (float*)d_out;

    const int B = in_sizes[0] / TDIM;          // x is (B, T, 1)
    const int wavesPerBlock = 4;
    const int blocks = (B + wavesPerBlock - 1) / wavesPerBlock;

    rnn_wave_per_batch_f32<<<blocks, wavesPerBlock * 64, 0, stream>>>(
        x, W_ih, W_hh, b_ih, b_hh, fc_w, fc_b, out, B);
}